// Round 1
// baseline (2797.378 us; speedup 1.0000x reference)
//
#include <hip/hip_runtime.h>
#include <hip/hip_bf16.h>

// Granite-8B-like fused attention block on MI355X.
// Key insight: the paged-cache scatter->gather is an exact identity (disjoint
// pages, one slot per (b,s)), so page_table is ignored entirely.
//
// Pipeline: transpose weights (fp32[K,N] -> bf16[N,K]) -> fused QKV MFMA GEMM
// -> RoPE -> online-softmax GQA attention (softcap+causal) -> out-proj GEMM.
// ws layout (128 MiB): WT[10240][4096] bf16 (wqT|wkT|wvT|woT), QKV[4096][6144]
// bf16; CTX[4096][4096] bf16 aliases WT rows 0..4095 (dead after QKV GEMM).

#define S_    1024
#define NQKV  6144
#define SCALE_   0.08838834764831845f
#define SOFTCAP_ 50.0f

typedef __bf16 bf16x8 __attribute__((ext_vector_type(8)));
typedef float  f32x4  __attribute__((ext_vector_type(4)));
typedef unsigned int  u32;
typedef unsigned short u16;

static __device__ __forceinline__ u16 f2bf(float f) {
  union { float f; u32 u; } v; v.f = f;
  u32 u = v.u;
  u32 r = u + 0x7FFFu + ((u >> 16) & 1u);   // round-to-nearest-even
  return (u16)(r >> 16);
}
static __device__ __forceinline__ float bf2f(u16 s) {
  union { u32 u; float f; } v; v.u = ((u32)s) << 16; return v.f;
}

// ---- weight transpose + cast: W fp32 [4096][N] -> WT bf16 [N][4096] ----
__global__ __launch_bounds__(256) void transpose_w(const float* __restrict__ W,
                                                   u16* __restrict__ WT, int N) {
  __shared__ float t[32][33];
  const int K = 4096;
  int n0 = blockIdx.x * 32, k0 = blockIdx.y * 32;
  int tx = threadIdx.x & 31, ty = threadIdx.x >> 5;   // 32 x 8
#pragma unroll
  for (int j = 0; j < 4; ++j)
    t[ty + 8 * j][tx] = W[(size_t)(k0 + ty + 8 * j) * N + n0 + tx];
  __syncthreads();
#pragma unroll
  for (int j = 0; j < 4; ++j)
    WT[(size_t)(n0 + ty + 8 * j) * K + k0 + tx] = f2bf(t[tx][ty + 8 * j]);
}

// ---- MFMA GEMM: A[M,K] (fp32 or bf16) x Bt[N,K] bf16 -> C[M,N] ----
// 128x128 tile, BK=32, 4 waves each own a 64x64 quadrant (4x4 16x16 frags).
template <bool A_BF16, bool OUT_BF16>
__global__ __launch_bounds__(256) void gemm_mfma(const void* __restrict__ Ap,
                                                 const u16* __restrict__ Bt,
                                                 void* __restrict__ Cp,
                                                 int N, int K) {
  __shared__ u16 As[128 * 32];   // [row][k] bf16
  __shared__ u16 Bs[128 * 32];   // [n][k]  bf16
  int tid = threadIdx.x;
  int wave = tid >> 6, lane = tid & 63;
  int quad = lane >> 4, l16 = lane & 15;
  int wrow = (wave >> 1) * 64, wcol = (wave & 1) * 64;
  int m0 = blockIdx.y * 128, n0 = blockIdx.x * 128;
  const int Kh = K >> 1;

  f32x4 acc[4][4];
#pragma unroll
  for (int i = 0; i < 4; ++i)
#pragma unroll
    for (int j = 0; j < 4; ++j)
#pragma unroll
      for (int c = 0; c < 4; ++c) acc[i][j][c] = 0.0f;

  for (int k0 = 0; k0 < K; k0 += 32) {
#pragma unroll
    for (int i = 0; i < 8; ++i) {           // stage A and B: 2048 u32 each
      int e = tid + 256 * i;
      int r = e >> 4, k2 = e & 15;
      u32 pa;
      if (A_BF16) {
        pa = ((const u32*)Ap)[(size_t)(m0 + r) * Kh + (k0 >> 1) + k2];
      } else {
        float2 fv = ((const float2*)Ap)[(size_t)(m0 + r) * Kh + (k0 >> 1) + k2];
        pa = (u32)f2bf(fv.x) | ((u32)f2bf(fv.y) << 16);
      }
      ((u32*)As)[r * 16 + k2] = pa;
      ((u32*)Bs)[r * 16 + k2] =
          ((const u32*)Bt)[(size_t)(n0 + r) * Kh + (k0 >> 1) + k2];
    }
    __syncthreads();
    bf16x8 af[4], bfr[4];
#pragma unroll
    for (int fi = 0; fi < 4; ++fi) {
      af[fi]  = *(const bf16x8*)&As[(wrow + fi * 16 + l16) * 32 + quad * 8];
      bfr[fi] = *(const bf16x8*)&Bs[(wcol + fi * 16 + l16) * 32 + quad * 8];
    }
#pragma unroll
    for (int mf = 0; mf < 4; ++mf)
#pragma unroll
      for (int nf = 0; nf < 4; ++nf)
        acc[mf][nf] = __builtin_amdgcn_mfma_f32_16x16x32_bf16(
            af[mf], bfr[nf], acc[mf][nf], 0, 0, 0);
    __syncthreads();
  }
  // epilogue: D[row = quad*4+reg][col = l16] per 16x16 frag (HW-verified map)
#pragma unroll
  for (int mf = 0; mf < 4; ++mf)
#pragma unroll
    for (int nf = 0; nf < 4; ++nf)
#pragma unroll
      for (int r = 0; r < 4; ++r) {
        int row = m0 + wrow + mf * 16 + quad * 4 + r;
        int col = n0 + wcol + nf * 16 + l16;
        float v = acc[mf][nf][r];
        if (OUT_BF16) ((u16*)Cp)[(size_t)row * N + col] = f2bf(v);
        else          ((float*)Cp)[(size_t)row * N + col] = v;
      }
}

// ---- RoPE in-place on QKV (Q heads 0..31, K heads 32..39; V untouched) ----
__global__ __launch_bounds__(256) void rope_kernel(u16* __restrict__ QKV,
                                                   const float* __restrict__ cosT,
                                                   const float* __restrict__ sinT) {
  int row = blockIdx.x;            // 0..4095 = b*S + s
  int s = row & (S_ - 1);
  size_t base = (size_t)row * NQKV;
#pragma unroll
  for (int i = 0; i < 10; ++i) {
    int e = threadIdx.x + 256 * i; // 0..2559 = 40 heads * 64 pairs
    int head = e >> 6, d = e & 63;
    int col = head * 128 + d;
    float c = cosT[s * 128 + d];
    float sn = sinT[s * 128 + d];
    float x1 = bf2f(QKV[base + col]);
    float x2 = bf2f(QKV[base + col + 64]);
    QKV[base + col]      = f2bf(x1 * c - x2 * sn);
    QKV[base + col + 64] = f2bf(x2 * c + x1 * sn);
  }
}

// ---- attention: block = (b, h, 16 q-rows); 4 waves x 4 rows each ----
// lane = key index for scores (kT[d][key], +1 pad => conflict-free),
// lane = dim-pair index for PV. Online softmax, softcap, causal.
__global__ __launch_bounds__(256) void attn_kernel(const u16* __restrict__ QKV,
                                                   u16* __restrict__ ctx) {
  __shared__ float kT[128 * 65];   // [d][key], padded
  __shared__ u32   vs[64 * 64];    // [key][dim-pair] bf16x2
  __shared__ float qs[16 * 128];   // [row][d]
  __shared__ float ps[4][256];     // per-wave P rows
  int bx = blockIdx.x;
  int qc = bx & 63, h = (bx >> 6) & 31, b = bx >> 11;
  int kvh = h >> 2;
  int q0 = qc * 16;
  int tid = threadIdx.x, wave = tid >> 6, lane = tid & 63;

#pragma unroll
  for (int i = 0; i < 8; ++i) {    // q tile: 16 rows x 128
    int e = tid + 256 * i;
    int r = e >> 7, d = e & 127;
    qs[e] = bf2f(QKV[(size_t)(b * S_ + q0 + r) * NQKV + h * 128 + d]);
  }
  float m[4], l[4], o0[4], o1[4];
#pragma unroll
  for (int i = 0; i < 4; ++i) { m[i] = -3e30f; l[i] = 0.f; o0[i] = 0.f; o1[i] = 0.f; }

  int cend = (q0 + 15) >> 6;
  for (int c = 0; c <= cend; ++c) {
#pragma unroll 4
    for (int i = 0; i < 32; ++i) { // K chunk: 64 keys x 128 d, transposed
      int e = tid + 256 * i;
      int j = e >> 7, d = e & 127;
      kT[d * 65 + j] =
          bf2f(QKV[(size_t)(b * S_ + c * 64 + j) * NQKV + 4096 + kvh * 128 + d]);
    }
#pragma unroll 4
    for (int i = 0; i < 16; ++i) { // V chunk as bf16 pairs
      int e = tid + 256 * i;
      int j = e >> 6, dp = e & 63;
      vs[j * 64 + dp] = ((const u32*)QKV)[((size_t)(b * S_ + c * 64 + j) * NQKV +
                                           5120 + kvh * 128) / 2 + dp];
    }
    __syncthreads();

    float sacc[4] = {0.f, 0.f, 0.f, 0.f};
#pragma unroll 4
    for (int d = 0; d < 128; ++d) {
      float kv = kT[d * 65 + lane];
#pragma unroll
      for (int i = 0; i < 4; ++i) sacc[i] += qs[(wave * 4 + i) * 128 + d] * kv;
    }
    int key = c * 64 + lane;
#pragma unroll
    for (int i = 0; i < 4; ++i) {
      int sr = q0 + wave * 4 + i;
      float sc = sacc[i] * SCALE_;
      sc = SOFTCAP_ * tanhf(sc * (1.0f / SOFTCAP_));
      if (key > sr) sc = -1e30f;
      float cm = sc;
#pragma unroll
      for (int off = 32; off >= 1; off >>= 1) cm = fmaxf(cm, __shfl_xor(cm, off, 64));
      float mn = fmaxf(m[i], cm);
      float alpha = __expf(m[i] - mn);
      float p = __expf(sc - mn);
      float psum = p;
#pragma unroll
      for (int off = 32; off >= 1; off >>= 1) psum += __shfl_xor(psum, off, 64);
      l[i] = l[i] * alpha + psum;
      o0[i] *= alpha; o1[i] *= alpha;
      m[i] = mn;
      ps[wave][i * 64 + lane] = p;
    }
#pragma unroll 4
    for (int j = 0; j < 64; ++j) { // PV: lane owns dims {2*lane, 2*lane+1}
      u32 v = vs[j * 64 + lane];
      union { u32 u; float f; } lo, hi;
      lo.u = v << 16; hi.u = v & 0xFFFF0000u;
#pragma unroll
      for (int i = 0; i < 4; ++i) {
        float p = ps[wave][i * 64 + j];
        o0[i] += p * lo.f;
        o1[i] += p * hi.f;
      }
    }
    __syncthreads();
  }
#pragma unroll
  for (int i = 0; i < 4; ++i) {
    int sr = q0 + wave * 4 + i;
    float inv = 1.0f / l[i];
    u32 packed = (u32)f2bf(o0[i] * inv) | ((u32)f2bf(o1[i] * inv) << 16);
    ((u32*)ctx)[(size_t)(b * S_ + sr) * 2048 + (size_t)h * 64 + lane] = packed;
  }
}

extern "C" void kernel_launch(void* const* d_in, const int* in_sizes, int n_in,
                              void* d_out, int out_size, void* d_ws, size_t ws_size,
                              hipStream_t stream) {
  (void)in_sizes; (void)n_in; (void)out_size; (void)ws_size;
  const float* hidden = (const float*)d_in[0];
  const float* wq = (const float*)d_in[1];
  const float* wk = (const float*)d_in[2];
  const float* wv = (const float*)d_in[3];
  const float* wo = (const float*)d_in[4];
  const float* cosT = (const float*)d_in[5];
  const float* sinT = (const float*)d_in[6];
  // d_in[7] = page_table: unused (scatter+gather round-trip is the identity)

  u16* WT  = (u16*)d_ws;                         // [10240][4096] bf16 (84 MB)
  u16* QKV = WT + (size_t)10240 * 4096;          // [4096][6144] bf16 (50 MB)
  u16* CTX = WT;                                 // aliases dead wq/wk/wv region

  // weight transposes -> bf16 [N][K]
  transpose_w<<<dim3(4096 / 32, 128), 256, 0, stream>>>(wq, WT, 4096);
  transpose_w<<<dim3(1024 / 32, 128), 256, 0, stream>>>(wk, WT + (size_t)4096 * 4096, 1024);
  transpose_w<<<dim3(1024 / 32, 128), 256, 0, stream>>>(wv, WT + (size_t)5120 * 4096, 1024);
  transpose_w<<<dim3(4096 / 32, 128), 256, 0, stream>>>(wo, WT + (size_t)6144 * 4096, 4096);

  // fused QKV GEMM: hidden fp32 [4096,4096] x WT[0..6143] -> QKV bf16
  gemm_mfma<false, true><<<dim3(6144 / 128, 4096 / 128), 256, 0, stream>>>(
      hidden, WT, QKV, 6144, 4096);
  rope_kernel<<<4096, 256, 0, stream>>>(QKV, cosT, sinT);
  attn_kernel<<<8192, 256, 0, stream>>>(QKV, CTX);
  // out-proj: CTX bf16 [4096,4096] x woT -> d_out fp32
  gemm_mfma<true, false><<<dim3(4096 / 128, 4096 / 128), 256, 0, stream>>>(
      CTX, WT + (size_t)6144 * 4096, d_out, 4096, 4096);
}